// Round 10
// baseline (155.915 us; speedup 1.0000x reference)
//
#include <hip/hip_runtime.h>
#include <math.h>

#define NN 512
#define CC 256
#define HH 8
#define DH 32

typedef float vf4 __attribute__((ext_vector_type(4)));

// ---------------- Kernel A: projections + Wp-fold ----------------
// grid = 512 (one n per block), block = 256
__global__ __launch_bounds__(256) void proj_kernel(
    const float* __restrict__ xq, const float* __restrict__ xk, const float* __restrict__ xv,
    const float* __restrict__ Wq, const float* __restrict__ bq,
    const float* __restrict__ Wk, const float* __restrict__ bk,
    const float* __restrict__ Wv, const float* __restrict__ bv,
    const float* __restrict__ Wp, const float* __restrict__ bp,
    float* __restrict__ qf, float* __restrict__ kf, float* __restrict__ vf,
    float* __restrict__ qw, float* __restrict__ qbp)
{
    __shared__ float x_lds[3][CC];
    __shared__ float q_lds[CC];
    const int t = threadIdx.x;
    const int n = blockIdx.x;

    if (t < 192) {
        int X = t >> 6, c4 = (t & 63) * 4;
        const float* xs = (X == 0) ? xq : (X == 1) ? xk : xv;
        *reinterpret_cast<float4*>(&x_lds[X][c4]) =
            *reinterpret_cast<const float4*>(xs + (size_t)n * CC + c4);
    }
    __syncthreads();

    const int j = t;
    {
        float accq = 0.f, acck = 0.f, accv = 0.f;
        const float* wq = Wq + (size_t)j * CC;
        const float* wk = Wk + (size_t)j * CC;
        const float* wv = Wv + (size_t)j * CC;
        #pragma unroll 4
        for (int k4 = 0; k4 < CC / 4; ++k4) {
            float4 a = *reinterpret_cast<const float4*>(wq + k4 * 4);
            float4 b = *reinterpret_cast<const float4*>(wk + k4 * 4);
            float4 d = *reinterpret_cast<const float4*>(wv + k4 * 4);
            const float* x0 = &x_lds[0][k4 * 4];
            const float* x1 = &x_lds[1][k4 * 4];
            const float* x2 = &x_lds[2][k4 * 4];
            accq += x0[0]*a.x + x0[1]*a.y + x0[2]*a.z + x0[3]*a.w;
            acck += x1[0]*b.x + x1[1]*b.y + x1[2]*b.z + x1[3]*b.w;
            accv += x2[0]*d.x + x2[1]*d.y + x2[2]*d.z + x2[3]*d.w;
        }
        float vq = accq + bq[j];
        kf[(size_t)n * CC + j] = acck + bk[j];
        vf[(size_t)n * CC + j] = accv + bv[j];
        qf[(size_t)n * CC + j] = vq;
        q_lds[j] = vq;
    }
    __syncthreads();

    // qw fold: thread -> (head-pair hp, j-quad jq); float4 Wp loads
    {
        const int jq = t & 63;
        const int hp = t >> 6;
        const int h0 = 2 * hp, h1 = h0 + 1;
        float4 a0 = {0.f, 0.f, 0.f, 0.f}, a1 = {0.f, 0.f, 0.f, 0.f};
        #pragma unroll
        for (int cc = 0; cc < DH; ++cc) {
            float q0 = q_lds[h0 * DH + cc];
            float q1 = q_lds[h1 * DH + cc];
            float4 w0 = *reinterpret_cast<const float4*>(Wp + (size_t)(h0 * DH + cc) * CC + jq * 4);
            float4 w1 = *reinterpret_cast<const float4*>(Wp + (size_t)(h1 * DH + cc) * CC + jq * 4);
            a0.x += q0 * w0.x; a0.y += q0 * w0.y; a0.z += q0 * w0.z; a0.w += q0 * w0.w;
            a1.x += q1 * w1.x; a1.y += q1 * w1.y; a1.z += q1 * w1.z; a1.w += q1 * w1.w;
        }
        *reinterpret_cast<float4*>(qw + ((size_t)n * HH + h0) * CC + jq * 4) = a0;
        *reinterpret_cast<float4*>(qw + ((size_t)n * HH + h1) * CC + jq * 4) = a1;
    }
    if (t < HH) {
        float s = 0.f;
        for (int cc = 0; cc < DH; ++cc) s += q_lds[t * DH + cc] * bp[t * DH + cc];
        qbp[(size_t)n * HH + t] = s;
    }
}

// 16-lane tree reduce of 8 head-partials; lane c (0..15) ends with head
// h = (c&1)*4 + (c&2) + ((c>>2)&1) in u0 (valid for c<8; c>=8 duplicates).
__device__ __forceinline__ float reduce8(const float a[HH], int c) {
    const bool b1 = (c & 1), b2 = (c & 2), b4 = (c & 4);
    float t0 = b1 ? a[0] : a[4], t1 = b1 ? a[1] : a[5],
          t2 = b1 ? a[2] : a[6], t3 = b1 ? a[3] : a[7];
    float r0 = (b1 ? a[4] : a[0]) + __shfl_xor(t0, 1);
    float r1 = (b1 ? a[5] : a[1]) + __shfl_xor(t1, 1);
    float r2 = (b1 ? a[6] : a[2]) + __shfl_xor(t2, 1);
    float r3 = (b1 ? a[7] : a[3]) + __shfl_xor(t3, 1);
    t0 = b2 ? r0 : r2; t1 = b2 ? r1 : r3;
    float s0 = (b2 ? r2 : r0) + __shfl_xor(t0, 2);
    float s1 = (b2 ? r3 : r1) + __shfl_xor(t1, 2);
    t0 = b4 ? s0 : s1;
    float u0 = (b4 ? s1 : s0) + __shfl_xor(t0, 4);
    u0 += __shfl_xor(u0, 8);
    return u0;
}

// ---------------- Kernel B: scores = q.k^T + E.qw over a 64-row slab ----------------
// grid = 4096: block b -> (n = b>>3, slab = b&7); block = 256 (4 waves),
// wave v owns rows m in [slab*64 + v*16, +16). Writes scores[n][h][m] (pre-softmax).
__global__ __launch_bounds__(256) void escore_kernel(
    const float* __restrict__ E, const float* __restrict__ qf,
    const float* __restrict__ kf, const float* __restrict__ qw,
    float* __restrict__ scores)
{
    const int b = blockIdx.x;
    const int n = b >> 3, slab = b & 7;
    const int m0 = slab * 64;
    const int t = threadIdx.x;
    const int v = t >> 6, l = t & 63;
    const int r = l >> 4, c = l & 15;

    __shared__ float qw_lds[HH][CC];      // 8 KB
    __shared__ float q_lds[CC];           // 1 KB
    __shared__ float s_out[HH][68];       // 2.2 KB, padded: bank = (4h+row)%32

    {
        const float4* src = reinterpret_cast<const float4*>(qw + (size_t)n * HH * CC);
        reinterpret_cast<float4*>(qw_lds)[t] = src[t];
        reinterpret_cast<float4*>(qw_lds)[t + 256] = src[t + 256];
    }
    if (t < 64)
        reinterpret_cast<float4*>(q_lds)[t] =
            reinterpret_cast<const float4*>(qf + (size_t)n * CC)[t];
    __syncthreads();

    const int mrow = m0 + v * 16 + r;      // rows mrow + 4*it, it=0..3

    float acc[4][HH];
    #pragma unroll
    for (int it = 0; it < 4; ++it)
        #pragma unroll
        for (int h = 0; h < HH; ++h) acc[it][h] = 0.f;

    // ---- k-dots: chunk (co,c) belongs to head 2co + (c>=8) ----
    #pragma unroll
    for (int co = 0; co < 4; ++co) {
        const int o = co * 64 + c * 4;
        float4 q4 = *reinterpret_cast<const float4*>(&q_lds[o]);
        #pragma unroll
        for (int it = 0; it < 4; ++it) {
            float4 k4 = *reinterpret_cast<const float4*>(
                kf + (size_t)(mrow + it * 4) * CC + o);
            float kd = k4.x*q4.x + k4.y*q4.y + k4.z*q4.z + k4.w*q4.w;
            acc[it][2*co  ] += (c & 8) ? 0.f : kd;
            acc[it][2*co+1] += (c & 8) ? kd : 0.f;
        }
    }

    // ---- E-dots: every chunk contributes to all 8 heads ----
    const float* Ebase = E + ((size_t)n * NN) * CC;
    #pragma unroll
    for (int co = 0; co < 4; ++co) {
        const int o = co * 64 + c * 4;
        vf4 e4[4];
        #pragma unroll
        for (int it = 0; it < 4; ++it)
            e4[it] = __builtin_nontemporal_load(reinterpret_cast<const vf4*>(
                Ebase + (size_t)(mrow + it * 4) * CC + o));
        #pragma unroll
        for (int h = 0; h < HH; ++h) {
            float4 wv = *reinterpret_cast<const float4*>(&qw_lds[h][o]);
            #pragma unroll
            for (int it = 0; it < 4; ++it)
                acc[it][h] += e4[it][0]*wv.x + e4[it][1]*wv.y +
                              e4[it][2]*wv.z + e4[it][3]*wv.w;
        }
    }

    // ---- reduce + stage to LDS ----
    #pragma unroll
    for (int it = 0; it < 4; ++it) {
        float u0 = reduce8(acc[it], c);
        if (!(c & 8)) {
            int h = (c & 1) * 4 + (c & 2) + ((c >> 2) & 1);
            s_out[h][v * 16 + it * 4 + r] = u0;
        }
    }
    __syncthreads();

    // ---- coalesced flush: scores[n][h][m0+row] ----
    {
        int h0 = t >> 6, row = t & 63;
        scores[((size_t)n * HH + h0) * NN + m0 + row] = s_out[h0][row];
        int h1 = h0 + 4;
        scores[((size_t)n * HH + h1) * NN + m0 + row] = s_out[h1][row];
    }
}

// ---------------- Kernel C: softmax + attn write + hidden ----------------
// grid = 512 (one n per block), block = 512; wave w handles head w
__global__ __launch_bounds__(512) void softmax_hidden_kernel(
    const float* __restrict__ scores, const float* __restrict__ qbp,
    const float* __restrict__ vf,
    float* __restrict__ attn_out, float* __restrict__ out_hidden)
{
    const int n = blockIdx.x;
    const int t = threadIdx.x;
    const int w = t >> 6, l = t & 63;

    __shared__ float s_lds[HH][NN + 4];   // 16.1 KB (probs)
    __shared__ float part_lds[HH][CC];    // 8 KB (hidden partials)

    {
        const int h = w;
        const float qb = qbp[(size_t)n * HH + h];
        const float scale = 0.17677669529663687f;  // 1/sqrt(32)
        const float* sp = scores + ((size_t)n * HH + h) * NN;
        float vals[8];
        float mx = -1e30f;
        #pragma unroll
        for (int i = 0; i < 8; ++i) {
            vals[i] = (sp[l + i * 64] + qb) * scale;
            mx = fmaxf(mx, vals[i]);
        }
        #pragma unroll
        for (int off = 32; off > 0; off >>= 1) mx = fmaxf(mx, __shfl_xor(mx, off));
        float sum = 0.f;
        #pragma unroll
        for (int i = 0; i < 8; ++i) { vals[i] = __expf(vals[i] - mx); sum += vals[i]; }
        #pragma unroll
        for (int off = 32; off > 0; off >>= 1) sum += __shfl_xor(sum, off);
        float inv = 1.0f / sum;
        #pragma unroll
        for (int i = 0; i < 8; ++i) {
            float p = vals[i] * inv;
            int m = l + i * 64;
            s_lds[h][m] = p;
            __builtin_nontemporal_store(p, attn_out + ((size_t)h * NN + n) * NN + m);
        }
    }
    __syncthreads();

    // hidden[n][j] = sum_m attn[h][m] * v[m][j], h = j>>5 (v is L2-resident)
    {
        const int quad = t & 63;           // output cols quad*4..quad*4+3
        const int slice = w;               // m slice of 64
        const int h = quad >> 3;
        float4 a4 = {0.f, 0.f, 0.f, 0.f};
        const float* vb = vf + quad * 4;
        for (int mm = 0; mm < 64; ++mm) {
            int m = slice * 64 + mm;
            float a = s_lds[h][m];
            float4 vv = *reinterpret_cast<const float4*>(vb + (size_t)m * CC);
            a4.x += a * vv.x; a4.y += a * vv.y; a4.z += a * vv.z; a4.w += a * vv.w;
        }
        *reinterpret_cast<float4*>(&part_lds[slice][quad * 4]) = a4;
    }
    __syncthreads();
    if (t < 256) {
        float s = 0.f;
        #pragma unroll
        for (int sl = 0; sl < 8; ++sl) s += part_lds[sl][t];
        out_hidden[(size_t)n * CC + t] = s;
    }
}

// ---------------- launch ----------------
extern "C" void kernel_launch(void* const* d_in, const int* in_sizes, int n_in,
                              void* d_out, int out_size, void* d_ws, size_t ws_size,
                              hipStream_t stream) {
    const float* xq = (const float*)d_in[0];
    const float* xk = (const float*)d_in[1];
    const float* xv = (const float*)d_in[2];
    const float* E  = (const float*)d_in[3];
    const float* Wq = (const float*)d_in[4];
    const float* bq = (const float*)d_in[5];
    const float* Wk = (const float*)d_in[6];
    const float* bk = (const float*)d_in[7];
    const float* Wv = (const float*)d_in[8];
    const float* bv = (const float*)d_in[9];
    const float* Wp = (const float*)d_in[10];
    const float* bp = (const float*)d_in[11];

    float* ws = (float*)d_ws;
    float* qf     = ws;                          // 512*256
    float* kf     = qf + NN * CC;                // 512*256
    float* vf     = kf + NN * CC;                // 512*256
    float* qw     = vf + NN * CC;                // 512*8*256
    float* qbp    = qw + (size_t)NN * HH * CC;   // 512*8
    float* scores = qbp + NN * HH;               // 512*8*512 (pre-softmax)

    float* out_hidden = (float*)d_out;            // 512*256
    float* out_attn   = out_hidden + NN * CC;     // 8*512*512

    proj_kernel<<<NN, 256, 0, stream>>>(xq, xk, xv, Wq, bq, Wk, bk, Wv, bv, Wp, bp,
                                        qf, kf, vf, qw, qbp);
    escore_kernel<<<NN * 8, 256, 0, stream>>>(E, qf, kf, qw, scores);
    softmax_hidden_kernel<<<NN, 512, 0, stream>>>(scores, qbp, vf, out_attn, out_hidden);
}

// Round 12
// 127.612 us; speedup vs baseline: 1.2218x; 1.2218x over previous
//
#include <hip/hip_runtime.h>
#include <math.h>

#define NN 512
#define CC 256
#define HH 8
#define DH 32

typedef float vf4 __attribute__((ext_vector_type(4)));

// ---------------- Kernel A: projections + Wp-fold ----------------
// grid = 512 (one n per block), block = 256
__global__ __launch_bounds__(256) void proj_kernel(
    const float* __restrict__ xq, const float* __restrict__ xk, const float* __restrict__ xv,
    const float* __restrict__ Wq, const float* __restrict__ bq,
    const float* __restrict__ Wk, const float* __restrict__ bk,
    const float* __restrict__ Wv, const float* __restrict__ bv,
    const float* __restrict__ Wp, const float* __restrict__ bp,
    float* __restrict__ qf, float* __restrict__ kf, float* __restrict__ vf,
    float* __restrict__ qw, float* __restrict__ qbp)
{
    __shared__ float x_lds[3][CC];
    __shared__ float q_lds[CC];
    const int t = threadIdx.x;
    const int n = blockIdx.x;

    if (t < 192) {
        int X = t >> 6, c4 = (t & 63) * 4;
        const float* xs = (X == 0) ? xq : (X == 1) ? xk : xv;
        *reinterpret_cast<float4*>(&x_lds[X][c4]) =
            *reinterpret_cast<const float4*>(xs + (size_t)n * CC + c4);
    }
    __syncthreads();

    const int j = t;
    {
        float accq = 0.f, acck = 0.f, accv = 0.f;
        const float* wq = Wq + (size_t)j * CC;
        const float* wk = Wk + (size_t)j * CC;
        const float* wv = Wv + (size_t)j * CC;
        #pragma unroll 4
        for (int k4 = 0; k4 < CC / 4; ++k4) {
            float4 a = *reinterpret_cast<const float4*>(wq + k4 * 4);
            float4 b = *reinterpret_cast<const float4*>(wk + k4 * 4);
            float4 d = *reinterpret_cast<const float4*>(wv + k4 * 4);
            const float* x0 = &x_lds[0][k4 * 4];
            const float* x1 = &x_lds[1][k4 * 4];
            const float* x2 = &x_lds[2][k4 * 4];
            accq += x0[0]*a.x + x0[1]*a.y + x0[2]*a.z + x0[3]*a.w;
            acck += x1[0]*b.x + x1[1]*b.y + x1[2]*b.z + x1[3]*b.w;
            accv += x2[0]*d.x + x2[1]*d.y + x2[2]*d.z + x2[3]*d.w;
        }
        float vq = accq + bq[j];
        kf[(size_t)n * CC + j] = acck + bk[j];
        vf[(size_t)n * CC + j] = accv + bv[j];
        qf[(size_t)n * CC + j] = vq;
        q_lds[j] = vq;
    }
    __syncthreads();

    // qw fold: thread -> (head-pair hp, j-quad jq); float4 Wp loads
    {
        const int jq = t & 63;
        const int hp = t >> 6;
        const int h0 = 2 * hp, h1 = h0 + 1;
        float4 a0 = {0.f, 0.f, 0.f, 0.f}, a1 = {0.f, 0.f, 0.f, 0.f};
        #pragma unroll
        for (int cc = 0; cc < DH; ++cc) {
            float q0 = q_lds[h0 * DH + cc];
            float q1 = q_lds[h1 * DH + cc];
            float4 w0 = *reinterpret_cast<const float4*>(Wp + (size_t)(h0 * DH + cc) * CC + jq * 4);
            float4 w1 = *reinterpret_cast<const float4*>(Wp + (size_t)(h1 * DH + cc) * CC + jq * 4);
            a0.x += q0 * w0.x; a0.y += q0 * w0.y; a0.z += q0 * w0.z; a0.w += q0 * w0.w;
            a1.x += q1 * w1.x; a1.y += q1 * w1.y; a1.z += q1 * w1.z; a1.w += q1 * w1.w;
        }
        *reinterpret_cast<float4*>(qw + ((size_t)n * HH + h0) * CC + jq * 4) = a0;
        *reinterpret_cast<float4*>(qw + ((size_t)n * HH + h1) * CC + jq * 4) = a1;
    }
    if (t < HH) {
        float s = 0.f;
        for (int cc = 0; cc < DH; ++cc) s += q_lds[t * DH + cc] * bp[t * DH + cc];
        qbp[(size_t)n * HH + t] = s;
    }
}

// ---------------- Kernel B: scores_e = q . k^T per head (runs alone; kf L2-hot) ----------------
// grid = 512: b = h*64 + nt*8 + mt; 64x64 tile; writes esc[n][h][m]
__global__ __launch_bounds__(256) void escore_kernel(
    const float* __restrict__ qf, const float* __restrict__ kf, float* __restrict__ esc)
{
    const int b = blockIdx.x;
    const int h = b >> 6, nt = (b >> 3) & 7, mt = b & 7;
    const int n0 = nt * 64, m0 = mt * 64;
    const int t = threadIdx.x;

    __shared__ float q_t[64][33];
    __shared__ float k_t[64][33];

    #pragma unroll
    for (int it = 0; it < 2; ++it) {
        int idx = t + it * 256;
        int row = idx >> 3, c4 = (idx & 7) * 4;
        float4 qv = *reinterpret_cast<const float4*>(qf + (size_t)(n0 + row) * CC + h * DH + c4);
        float4 kv = *reinterpret_cast<const float4*>(kf + (size_t)(m0 + row) * CC + h * DH + c4);
        q_t[row][c4] = qv.x; q_t[row][c4+1] = qv.y; q_t[row][c4+2] = qv.z; q_t[row][c4+3] = qv.w;
        k_t[row][c4] = kv.x; k_t[row][c4+1] = kv.y; k_t[row][c4+2] = kv.z; k_t[row][c4+3] = kv.w;
    }
    __syncthreads();

    const int tx = t & 15, ty = t >> 4;
    float acc[4][4];
    #pragma unroll
    for (int i = 0; i < 4; ++i)
        #pragma unroll
        for (int jq = 0; jq < 4; ++jq) acc[i][jq] = 0.f;

    for (int cc = 0; cc < DH; ++cc) {
        float qa[4], kb[4];
        #pragma unroll
        for (int i = 0; i < 4; ++i) qa[i] = q_t[ty * 4 + i][cc];
        #pragma unroll
        for (int jq = 0; jq < 4; ++jq) kb[jq] = k_t[tx * 4 + jq][cc];
        #pragma unroll
        for (int i = 0; i < 4; ++i)
            #pragma unroll
            for (int jq = 0; jq < 4; ++jq) acc[i][jq] += qa[i] * kb[jq];
    }

    #pragma unroll
    for (int i = 0; i < 4; ++i) {
        float4 v = {acc[i][0], acc[i][1], acc[i][2], acc[i][3]};
        *reinterpret_cast<float4*>(
            esc + ((size_t)(n0 + ty * 4 + i) * HH + h) * NN + m0 + tx * 4) = v;
    }
}

// 16-lane tree reduce of 8 head-partials; lane c (0..15) ends with head
// h = (c&1)*4 + (c&2) + ((c>>2)&1) in u0 (valid for c<8; c>=8 duplicates).
__device__ __forceinline__ float reduce8(const float a[HH], int c) {
    const bool b1 = (c & 1), b2 = (c & 2), b4 = (c & 4);
    float t0 = b1 ? a[0] : a[4], t1 = b1 ? a[1] : a[5],
          t2 = b1 ? a[2] : a[6], t3 = b1 ? a[3] : a[7];
    float r0 = (b1 ? a[4] : a[0]) + __shfl_xor(t0, 1);
    float r1 = (b1 ? a[5] : a[1]) + __shfl_xor(t1, 1);
    float r2 = (b1 ? a[6] : a[2]) + __shfl_xor(t2, 1);
    float r3 = (b1 ? a[7] : a[3]) + __shfl_xor(t3, 1);
    t0 = b2 ? r0 : r2; t1 = b2 ? r1 : r3;
    float s0 = (b2 ? r2 : r0) + __shfl_xor(t0, 2);
    float s1 = (b2 ? r3 : r1) + __shfl_xor(t1, 2);
    t0 = b4 ? s0 : s1;
    float u0 = (b4 ? s1 : s0) + __shfl_xor(t0, 4);
    u0 += __shfl_xor(u0, 8);
    return u0;
}

// ---------------- Kernel C: scores_p = E . qw over a 64-row slab (E + qw ONLY) ----------------
// grid = 4096: block b -> (n = b>>3, slab = b&7); block = 256 (4 waves),
// wave v owns rows m in [slab*64 + v*16, +16). Writes scores[n][h][m].
__global__ __launch_bounds__(256) void estream_kernel(
    const float* __restrict__ E, const float* __restrict__ qw,
    float* __restrict__ scores)
{
    const int b = blockIdx.x;
    const int n = b >> 3, slab = b & 7;
    const int m0 = slab * 64;
    const int t = threadIdx.x;
    const int v = t >> 6, l = t & 63;
    const int r = l >> 4, c = l & 15;

    __shared__ float qw_lds[HH][CC];      // 8 KB
    __shared__ float s_out[HH][68];       // 2.2 KB

    {
        const float4* src = reinterpret_cast<const float4*>(qw + (size_t)n * HH * CC);
        reinterpret_cast<float4*>(qw_lds)[t] = src[t];
        reinterpret_cast<float4*>(qw_lds)[t + 256] = src[t + 256];
    }
    __syncthreads();

    const int mrow = m0 + v * 16 + r;      // rows mrow + 4*it, it=0..3

    float acc[4][HH];
    #pragma unroll
    for (int it = 0; it < 4; ++it)
        #pragma unroll
        for (int h = 0; h < HH; ++h) acc[it][h] = 0.f;

    const float* Ebase = E + ((size_t)n * NN) * CC;
    #pragma unroll
    for (int co = 0; co < 4; ++co) {
        const int o = co * 64 + c * 4;
        vf4 e4[4];
        #pragma unroll
        for (int it = 0; it < 4; ++it)
            e4[it] = __builtin_nontemporal_load(reinterpret_cast<const vf4*>(
                Ebase + (size_t)(mrow + it * 4) * CC + o));
        #pragma unroll
        for (int h = 0; h < HH; ++h) {
            float4 wv = *reinterpret_cast<const float4*>(&qw_lds[h][o]);
            #pragma unroll
            for (int it = 0; it < 4; ++it)
                acc[it][h] += e4[it][0]*wv.x + e4[it][1]*wv.y +
                              e4[it][2]*wv.z + e4[it][3]*wv.w;
        }
    }

    #pragma unroll
    for (int it = 0; it < 4; ++it) {
        float u0 = reduce8(acc[it], c);
        if (!(c & 8)) {
            int h = (c & 1) * 4 + (c & 2) + ((c >> 2) & 1);
            s_out[h][v * 16 + it * 4 + r] = u0;
        }
    }
    __syncthreads();

    // coalesced flush: scores[n][h][m0+row]
    {
        int h0 = t >> 6, row = t & 63;
        scores[((size_t)n * HH + h0) * NN + m0 + row] = s_out[h0][row];
        int h1 = h0 + 4;
        scores[((size_t)n * HH + h1) * NN + m0 + row] = s_out[h1][row];
    }
}

// ---------------- Kernel D: softmax(esc + scores) + attn write + hidden ----------------
// grid = 512 (one n per block), block = 512; wave w handles head w
__global__ __launch_bounds__(512) void softmax_hidden_kernel(
    const float* __restrict__ esc, const float* __restrict__ scores,
    const float* __restrict__ qbp, const float* __restrict__ vf,
    float* __restrict__ attn_out, float* __restrict__ out_hidden)
{
    const int n = blockIdx.x;
    const int t = threadIdx.x;
    const int w = t >> 6, l = t & 63;

    __shared__ float s_lds[HH][NN + 4];   // 16.1 KB (probs)
    __shared__ float part_lds[HH][CC];    // 8 KB (hidden partials)

    {
        const int h = w;
        const float qb = qbp[(size_t)n * HH + h];
        const float scale = 0.17677669529663687f;  // 1/sqrt(32)
        const float* ep = esc    + ((size_t)n * HH + h) * NN;
        const float* sp = scores + ((size_t)n * HH + h) * NN;
        float vals[8];
        float mx = -1e30f;
        #pragma unroll
        for (int i = 0; i < 8; ++i) {
            vals[i] = (ep[l + i * 64] + sp[l + i * 64] + qb) * scale;
            mx = fmaxf(mx, vals[i]);
        }
        #pragma unroll
        for (int off = 32; off > 0; off >>= 1) mx = fmaxf(mx, __shfl_xor(mx, off));
        float sum = 0.f;
        #pragma unroll
        for (int i = 0; i < 8; ++i) { vals[i] = __expf(vals[i] - mx); sum += vals[i]; }
        #pragma unroll
        for (int off = 32; off > 0; off >>= 1) sum += __shfl_xor(sum, off);
        float inv = 1.0f / sum;
        #pragma unroll
        for (int i = 0; i < 8; ++i) {
            float p = vals[i] * inv;
            int m = l + i * 64;
            s_lds[h][m] = p;
            __builtin_nontemporal_store(p, attn_out + ((size_t)h * NN + n) * NN + m);
        }
    }
    __syncthreads();

    // hidden[n][j] = sum_m attn[h][m] * v[m][j], h = j>>5 (E done -> vf stays in L2)
    {
        const int quad = t & 63;           // output cols quad*4..quad*4+3
        const int slice = w;               // m slice of 64
        const int h = quad >> 3;
        float4 a4 = {0.f, 0.f, 0.f, 0.f};
        const float* vb = vf + quad * 4;
        for (int mm = 0; mm < 64; ++mm) {
            int m = slice * 64 + mm;
            float a = s_lds[h][m];
            float4 vv = *reinterpret_cast<const float4*>(vb + (size_t)m * CC);
            a4.x += a * vv.x; a4.y += a * vv.y; a4.z += a * vv.z; a4.w += a * vv.w;
        }
        *reinterpret_cast<float4*>(&part_lds[slice][quad * 4]) = a4;
    }
    __syncthreads();
    if (t < 256) {
        float s = 0.f;
        #pragma unroll
        for (int sl = 0; sl < 8; ++sl) s += part_lds[sl][t];
        out_hidden[(size_t)n * CC + t] = s;
    }
}

// ---------------- launch ----------------
extern "C" void kernel_launch(void* const* d_in, const int* in_sizes, int n_in,
                              void* d_out, int out_size, void* d_ws, size_t ws_size,
                              hipStream_t stream) {
    const float* xq = (const float*)d_in[0];
    const float* xk = (const float*)d_in[1];
    const float* xv = (const float*)d_in[2];
    const float* E  = (const float*)d_in[3];
    const float* Wq = (const float*)d_in[4];
    const float* bq = (const float*)d_in[5];
    const float* Wk = (const float*)d_in[6];
    const float* bk = (const float*)d_in[7];
    const float* Wv = (const float*)d_in[8];
    const float* bv = (const float*)d_in[9];
    const float* Wp = (const float*)d_in[10];
    const float* bp = (const float*)d_in[11];

    float* ws = (float*)d_ws;
    float* qf     = ws;                          // 512*256
    float* kf     = qf + NN * CC;                // 512*256
    float* vf     = kf + NN * CC;                // 512*256
    float* qw     = vf + NN * CC;                // 512*8*256
    float* qbp    = qw + (size_t)NN * HH * CC;   // 512*8
    float* esc    = qbp + NN * HH;               // 512*8*512 (q.k^T scores)
    float* scores = esc + (size_t)NN * HH * NN;  // 512*8*512 (E.qw scores)

    float* out_hidden = (float*)d_out;            // 512*256
    float* out_attn   = out_hidden + NN * CC;     // 8*512*512

    proj_kernel<<<NN, 256, 0, stream>>>(xq, xk, xv, Wq, bq, Wk, bk, Wv, bv, Wp, bp,
                                        qf, kf, vf, qw, qbp);
    escore_kernel<<<512, 256, 0, stream>>>(qf, kf, esc);
    estream_kernel<<<NN * 8, 256, 0, stream>>>(E, qw, scores);
    softmax_hidden_kernel<<<NN, 512, 0, stream>>>(esc, scores, qbp, vf,
                                                  out_attn, out_hidden);
}

// Round 13
// 127.550 us; speedup vs baseline: 1.2224x; 1.0005x over previous
//
#include <hip/hip_runtime.h>
#include <math.h>

#define NN 512
#define CC 256
#define HH 8
#define DH 32

typedef float vf4 __attribute__((ext_vector_type(4)));

// ---------------- Kernel A: projections + Wp-fold ----------------
// grid = 512 (one n per block), block = 256
__global__ __launch_bounds__(256) void proj_kernel(
    const float* __restrict__ xq, const float* __restrict__ xk, const float* __restrict__ xv,
    const float* __restrict__ Wq, const float* __restrict__ bq,
    const float* __restrict__ Wk, const float* __restrict__ bk,
    const float* __restrict__ Wv, const float* __restrict__ bv,
    const float* __restrict__ Wp, const float* __restrict__ bp,
    float* __restrict__ qf, float* __restrict__ kf, float* __restrict__ vf,
    float* __restrict__ qw, float* __restrict__ qbp)
{
    __shared__ float x_lds[3][CC];
    __shared__ float q_lds[CC];
    const int t = threadIdx.x;
    const int n = blockIdx.x;

    if (t < 192) {
        int X = t >> 6, c4 = (t & 63) * 4;
        const float* xs = (X == 0) ? xq : (X == 1) ? xk : xv;
        *reinterpret_cast<float4*>(&x_lds[X][c4]) =
            *reinterpret_cast<const float4*>(xs + (size_t)n * CC + c4);
    }
    __syncthreads();

    const int j = t;
    {
        float accq = 0.f, acck = 0.f, accv = 0.f;
        const float* wq = Wq + (size_t)j * CC;
        const float* wk = Wk + (size_t)j * CC;
        const float* wv = Wv + (size_t)j * CC;
        #pragma unroll 4
        for (int k4 = 0; k4 < CC / 4; ++k4) {
            float4 a = *reinterpret_cast<const float4*>(wq + k4 * 4);
            float4 b = *reinterpret_cast<const float4*>(wk + k4 * 4);
            float4 d = *reinterpret_cast<const float4*>(wv + k4 * 4);
            const float* x0 = &x_lds[0][k4 * 4];
            const float* x1 = &x_lds[1][k4 * 4];
            const float* x2 = &x_lds[2][k4 * 4];
            accq += x0[0]*a.x + x0[1]*a.y + x0[2]*a.z + x0[3]*a.w;
            acck += x1[0]*b.x + x1[1]*b.y + x1[2]*b.z + x1[3]*b.w;
            accv += x2[0]*d.x + x2[1]*d.y + x2[2]*d.z + x2[3]*d.w;
        }
        float vq = accq + bq[j];
        kf[(size_t)n * CC + j] = acck + bk[j];
        vf[(size_t)n * CC + j] = accv + bv[j];
        qf[(size_t)n * CC + j] = vq;
        q_lds[j] = vq;
    }
    __syncthreads();

    // qw fold: thread -> (head-pair hp, j-quad jq); float4 Wp loads
    {
        const int jq = t & 63;
        const int hp = t >> 6;
        const int h0 = 2 * hp, h1 = h0 + 1;
        float4 a0 = {0.f, 0.f, 0.f, 0.f}, a1 = {0.f, 0.f, 0.f, 0.f};
        #pragma unroll
        for (int cc = 0; cc < DH; ++cc) {
            float q0 = q_lds[h0 * DH + cc];
            float q1 = q_lds[h1 * DH + cc];
            float4 w0 = *reinterpret_cast<const float4*>(Wp + (size_t)(h0 * DH + cc) * CC + jq * 4);
            float4 w1 = *reinterpret_cast<const float4*>(Wp + (size_t)(h1 * DH + cc) * CC + jq * 4);
            a0.x += q0 * w0.x; a0.y += q0 * w0.y; a0.z += q0 * w0.z; a0.w += q0 * w0.w;
            a1.x += q1 * w1.x; a1.y += q1 * w1.y; a1.z += q1 * w1.z; a1.w += q1 * w1.w;
        }
        *reinterpret_cast<float4*>(qw + ((size_t)n * HH + h0) * CC + jq * 4) = a0;
        *reinterpret_cast<float4*>(qw + ((size_t)n * HH + h1) * CC + jq * 4) = a1;
    }
    if (t < HH) {
        float s = 0.f;
        for (int cc = 0; cc < DH; ++cc) s += q_lds[t * DH + cc] * bp[t * DH + cc];
        qbp[(size_t)n * HH + t] = s;
    }
}

// ---------------- Kernel B: scores_e = q . k^T per head (runs alone; kf L2-hot) ----------------
// grid = 512: b = h*64 + nt*8 + mt; 64x64 tile; writes esc[n][h][m]
__global__ __launch_bounds__(256) void escore_kernel(
    const float* __restrict__ qf, const float* __restrict__ kf, float* __restrict__ esc)
{
    const int b = blockIdx.x;
    const int h = b >> 6, nt = (b >> 3) & 7, mt = b & 7;
    const int n0 = nt * 64, m0 = mt * 64;
    const int t = threadIdx.x;

    __shared__ float q_t[64][33];
    __shared__ float k_t[64][33];

    #pragma unroll
    for (int it = 0; it < 2; ++it) {
        int idx = t + it * 256;
        int row = idx >> 3, c4 = (idx & 7) * 4;
        float4 qv = *reinterpret_cast<const float4*>(qf + (size_t)(n0 + row) * CC + h * DH + c4);
        float4 kv = *reinterpret_cast<const float4*>(kf + (size_t)(m0 + row) * CC + h * DH + c4);
        q_t[row][c4] = qv.x; q_t[row][c4+1] = qv.y; q_t[row][c4+2] = qv.z; q_t[row][c4+3] = qv.w;
        k_t[row][c4] = kv.x; k_t[row][c4+1] = kv.y; k_t[row][c4+2] = kv.z; k_t[row][c4+3] = kv.w;
    }
    __syncthreads();

    const int tx = t & 15, ty = t >> 4;
    float acc[4][4];
    #pragma unroll
    for (int i = 0; i < 4; ++i)
        #pragma unroll
        for (int jq = 0; jq < 4; ++jq) acc[i][jq] = 0.f;

    for (int cc = 0; cc < DH; ++cc) {
        float qa[4], kb[4];
        #pragma unroll
        for (int i = 0; i < 4; ++i) qa[i] = q_t[ty * 4 + i][cc];
        #pragma unroll
        for (int jq = 0; jq < 4; ++jq) kb[jq] = k_t[tx * 4 + jq][cc];
        #pragma unroll
        for (int i = 0; i < 4; ++i)
            #pragma unroll
            for (int jq = 0; jq < 4; ++jq) acc[i][jq] += qa[i] * kb[jq];
    }

    #pragma unroll
    for (int i = 0; i < 4; ++i) {
        float4 v = {acc[i][0], acc[i][1], acc[i][2], acc[i][3]};
        *reinterpret_cast<float4*>(
            esc + ((size_t)(n0 + ty * 4 + i) * HH + h) * NN + m0 + tx * 4) = v;
    }
}

// 16-lane tree reduce of 8 head-partials; lane c (0..15) ends with head
// h = (c&1)*4 + (c&2) + ((c>>2)&1) in u0 (valid for c<8; c>=8 duplicates).
__device__ __forceinline__ float reduce8(const float a[HH], int c) {
    const bool b1 = (c & 1), b2 = (c & 2), b4 = (c & 4);
    float t0 = b1 ? a[0] : a[4], t1 = b1 ? a[1] : a[5],
          t2 = b1 ? a[2] : a[6], t3 = b1 ? a[3] : a[7];
    float r0 = (b1 ? a[4] : a[0]) + __shfl_xor(t0, 1);
    float r1 = (b1 ? a[5] : a[1]) + __shfl_xor(t1, 1);
    float r2 = (b1 ? a[6] : a[2]) + __shfl_xor(t2, 1);
    float r3 = (b1 ? a[7] : a[3]) + __shfl_xor(t3, 1);
    t0 = b2 ? r0 : r2; t1 = b2 ? r1 : r3;
    float s0 = (b2 ? r2 : r0) + __shfl_xor(t0, 2);
    float s1 = (b2 ? r3 : r1) + __shfl_xor(t1, 2);
    t0 = b4 ? s0 : s1;
    float u0 = (b4 ? s1 : s0) + __shfl_xor(t0, 4);
    u0 += __shfl_xor(u0, 8);
    return u0;
}

// ---------------- Kernel C: scores_p = E . qw, full-row wave bursts ----------------
// grid = 4096: block b -> (n = b>>3, slab = b&7); block = 256 (4 waves).
// Wave v reads rows [slab*64 + v*16, +16); ONE instruction = ONE full 1KB row
// (lane l covers cols l*4..l*4+3) -> sequential DRAM pages, copy-kernel-like.
// qw lives in registers (lane l only needs qw[h][l*4..3]); no LDS in hot loop.
__global__ __launch_bounds__(256, 4) void estream_kernel(
    const float* __restrict__ E, const float* __restrict__ qw,
    float* __restrict__ scores)
{
    const int b = blockIdx.x;
    const int n = b >> 3, slab = b & 7;
    const int m0 = slab * 64;
    const int t = threadIdx.x;
    const int v = t >> 6, l = t & 63;
    const int c = l & 15;

    __shared__ float s_out[HH][68];       // 2.2 KB

    // qw fragments for this lane's column: 8 heads x float4 = 32 VGPRs (L2-hot)
    vf4 qwr[HH];
    #pragma unroll
    for (int h = 0; h < HH; ++h)
        qwr[h] = *reinterpret_cast<const vf4*>(qw + ((size_t)n * HH + h) * CC + l * 4);

    const float* Ebase = E + ((size_t)n * NN + m0 + v * 16) * CC;

    #pragma unroll
    for (int g = 0; g < 4; ++g) {
        // 4 rows in flight, each row one full-KB wave burst
        vf4 e4[4];
        #pragma unroll
        for (int it = 0; it < 4; ++it)
            e4[it] = __builtin_nontemporal_load(reinterpret_cast<const vf4*>(
                Ebase + (size_t)(g * 4 + it) * CC + l * 4));

        #pragma unroll
        for (int it = 0; it < 4; ++it) {
            float a[HH];
            #pragma unroll
            for (int h = 0; h < HH; ++h)
                a[h] = e4[it][0]*qwr[h][0] + e4[it][1]*qwr[h][1] +
                       e4[it][2]*qwr[h][2] + e4[it][3]*qwr[h][3];
            // reduce within 16-lane groups, then across the 4 groups
            float u0 = reduce8(a, c);
            u0 += __shfl_xor(u0, 16);
            u0 += __shfl_xor(u0, 32);
            if (l < 8) {
                int h = (c & 1) * 4 + (c & 2) + ((c >> 2) & 1);
                s_out[h][v * 16 + g * 4 + it] = u0;
            }
        }
    }
    __syncthreads();

    // coalesced flush: scores[n][h][m0+row]
    {
        int h0 = t >> 6, row = t & 63;
        scores[((size_t)n * HH + h0) * NN + m0 + row] = s_out[h0][row];
        int h1 = h0 + 4;
        scores[((size_t)n * HH + h1) * NN + m0 + row] = s_out[h1][row];
    }
}

// ---------------- Kernel D: softmax(esc + scores) + attn write + hidden ----------------
// grid = 512 (one n per block), block = 512; wave w handles head w
__global__ __launch_bounds__(512) void softmax_hidden_kernel(
    const float* __restrict__ esc, const float* __restrict__ scores,
    const float* __restrict__ qbp, const float* __restrict__ vf,
    float* __restrict__ attn_out, float* __restrict__ out_hidden)
{
    const int n = blockIdx.x;
    const int t = threadIdx.x;
    const int w = t >> 6, l = t & 63;

    __shared__ float s_lds[HH][NN + 4];   // 16.1 KB (probs)
    __shared__ float part_lds[HH][CC];    // 8 KB (hidden partials)

    {
        const int h = w;
        const float qb = qbp[(size_t)n * HH + h];
        const float scale = 0.17677669529663687f;  // 1/sqrt(32)
        const float* ep = esc    + ((size_t)n * HH + h) * NN;
        const float* sp = scores + ((size_t)n * HH + h) * NN;
        float vals[8];
        float mx = -1e30f;
        #pragma unroll
        for (int i = 0; i < 8; ++i) {
            vals[i] = (ep[l + i * 64] + sp[l + i * 64] + qb) * scale;
            mx = fmaxf(mx, vals[i]);
        }
        #pragma unroll
        for (int off = 32; off > 0; off >>= 1) mx = fmaxf(mx, __shfl_xor(mx, off));
        float sum = 0.f;
        #pragma unroll
        for (int i = 0; i < 8; ++i) { vals[i] = __expf(vals[i] - mx); sum += vals[i]; }
        #pragma unroll
        for (int off = 32; off > 0; off >>= 1) sum += __shfl_xor(sum, off);
        float inv = 1.0f / sum;
        #pragma unroll
        for (int i = 0; i < 8; ++i) {
            float p = vals[i] * inv;
            int m = l + i * 64;
            s_lds[h][m] = p;
            __builtin_nontemporal_store(p, attn_out + ((size_t)h * NN + n) * NN + m);
        }
    }
    __syncthreads();

    // hidden[n][j] = sum_m attn[h][m] * v[m][j], h = j>>5 (E done -> vf stays in L2)
    {
        const int quad = t & 63;           // output cols quad*4..quad*4+3
        const int slice = w;               // m slice of 64
        const int h = quad >> 3;
        float4 a4 = {0.f, 0.f, 0.f, 0.f};
        const float* vb = vf + quad * 4;
        for (int mm = 0; mm < 64; ++mm) {
            int m = slice * 64 + mm;
            float a = s_lds[h][m];
            float4 vv = *reinterpret_cast<const float4*>(vb + (size_t)m * CC);
            a4.x += a * vv.x; a4.y += a * vv.y; a4.z += a * vv.z; a4.w += a * vv.w;
        }
        *reinterpret_cast<float4*>(&part_lds[slice][quad * 4]) = a4;
    }
    __syncthreads();
    if (t < 256) {
        float s = 0.f;
        #pragma unroll
        for (int sl = 0; sl < 8; ++sl) s += part_lds[sl][t];
        out_hidden[(size_t)n * CC + t] = s;
    }
}

// ---------------- launch ----------------
extern "C" void kernel_launch(void* const* d_in, const int* in_sizes, int n_in,
                              void* d_out, int out_size, void* d_ws, size_t ws_size,
                              hipStream_t stream) {
    const float* xq = (const float*)d_in[0];
    const float* xk = (const float*)d_in[1];
    const float* xv = (const float*)d_in[2];
    const float* E  = (const float*)d_in[3];
    const float* Wq = (const float*)d_in[4];
    const float* bq = (const float*)d_in[5];
    const float* Wk = (const float*)d_in[6];
    const float* bk = (const float*)d_in[7];
    const float* Wv = (const float*)d_in[8];
    const float* bv = (const float*)d_in[9];
    const float* Wp = (const float*)d_in[10];
    const float* bp = (const float*)d_in[11];

    float* ws = (float*)d_ws;
    float* qf     = ws;                          // 512*256
    float* kf     = qf + NN * CC;                // 512*256
    float* vf     = kf + NN * CC;                // 512*256
    float* qw     = vf + NN * CC;                // 512*8*256
    float* qbp    = qw + (size_t)NN * HH * CC;   // 512*8
    float* esc    = qbp + NN * HH;               // 512*8*512 (q.k^T scores)
    float* scores = esc + (size_t)NN * HH * NN;  // 512*8*512 (E.qw scores)

    float* out_hidden = (float*)d_out;            // 512*256
    float* out_attn   = out_hidden + NN * CC;     // 8*512*512

    proj_kernel<<<NN, 256, 0, stream>>>(xq, xk, xv, Wq, bq, Wk, bk, Wv, bv, Wp, bp,
                                        qf, kf, vf, qw, qbp);
    escore_kernel<<<512, 256, 0, stream>>>(qf, kf, esc);
    estream_kernel<<<NN * 8, 256, 0, stream>>>(E, qw, scores);
    softmax_hidden_kernel<<<NN, 512, 0, stream>>>(esc, scores, qbp, vf,
                                                  out_attn, out_hidden);
}

// Round 14
// 123.109 us; speedup vs baseline: 1.2665x; 1.0361x over previous
//
#include <hip/hip_runtime.h>
#include <math.h>

#define NN 512
#define CC 256
#define HH 8
#define DH 32

typedef float vf4 __attribute__((ext_vector_type(4)));

// ---------------- Kernel A: projections + Wp-fold ----------------
// grid = 512 (one n per block), block = 256
__global__ __launch_bounds__(256) void proj_kernel(
    const float* __restrict__ xq, const float* __restrict__ xk, const float* __restrict__ xv,
    const float* __restrict__ Wq, const float* __restrict__ bq,
    const float* __restrict__ Wk, const float* __restrict__ bk,
    const float* __restrict__ Wv, const float* __restrict__ bv,
    const float* __restrict__ Wp, const float* __restrict__ bp,
    float* __restrict__ qf, float* __restrict__ kf, float* __restrict__ vf,
    float* __restrict__ qw, float* __restrict__ qbp)
{
    __shared__ float x_lds[3][CC];
    __shared__ float q_lds[CC];
    const int t = threadIdx.x;
    const int n = blockIdx.x;

    if (t < 192) {
        int X = t >> 6, c4 = (t & 63) * 4;
        const float* xs = (X == 0) ? xq : (X == 1) ? xk : xv;
        *reinterpret_cast<float4*>(&x_lds[X][c4]) =
            *reinterpret_cast<const float4*>(xs + (size_t)n * CC + c4);
    }
    __syncthreads();

    const int j = t;
    {
        float accq = 0.f, acck = 0.f, accv = 0.f;
        const float* wq = Wq + (size_t)j * CC;
        const float* wk = Wk + (size_t)j * CC;
        const float* wv = Wv + (size_t)j * CC;
        #pragma unroll 4
        for (int k4 = 0; k4 < CC / 4; ++k4) {
            float4 a = *reinterpret_cast<const float4*>(wq + k4 * 4);
            float4 b = *reinterpret_cast<const float4*>(wk + k4 * 4);
            float4 d = *reinterpret_cast<const float4*>(wv + k4 * 4);
            const float* x0 = &x_lds[0][k4 * 4];
            const float* x1 = &x_lds[1][k4 * 4];
            const float* x2 = &x_lds[2][k4 * 4];
            accq += x0[0]*a.x + x0[1]*a.y + x0[2]*a.z + x0[3]*a.w;
            acck += x1[0]*b.x + x1[1]*b.y + x1[2]*b.z + x1[3]*b.w;
            accv += x2[0]*d.x + x2[1]*d.y + x2[2]*d.z + x2[3]*d.w;
        }
        float vq = accq + bq[j];
        kf[(size_t)n * CC + j] = acck + bk[j];
        vf[(size_t)n * CC + j] = accv + bv[j];
        qf[(size_t)n * CC + j] = vq;
        q_lds[j] = vq;
    }
    __syncthreads();

    // qw fold: thread -> (head-pair hp, j-quad jq); float4 Wp loads
    {
        const int jq = t & 63;
        const int hp = t >> 6;
        const int h0 = 2 * hp, h1 = h0 + 1;
        float4 a0 = {0.f, 0.f, 0.f, 0.f}, a1 = {0.f, 0.f, 0.f, 0.f};
        #pragma unroll
        for (int cc = 0; cc < DH; ++cc) {
            float q0 = q_lds[h0 * DH + cc];
            float q1 = q_lds[h1 * DH + cc];
            float4 w0 = *reinterpret_cast<const float4*>(Wp + (size_t)(h0 * DH + cc) * CC + jq * 4);
            float4 w1 = *reinterpret_cast<const float4*>(Wp + (size_t)(h1 * DH + cc) * CC + jq * 4);
            a0.x += q0 * w0.x; a0.y += q0 * w0.y; a0.z += q0 * w0.z; a0.w += q0 * w0.w;
            a1.x += q1 * w1.x; a1.y += q1 * w1.y; a1.z += q1 * w1.z; a1.w += q1 * w1.w;
        }
        *reinterpret_cast<float4*>(qw + ((size_t)n * HH + h0) * CC + jq * 4) = a0;
        *reinterpret_cast<float4*>(qw + ((size_t)n * HH + h1) * CC + jq * 4) = a1;
    }
    if (t < HH) {
        float s = 0.f;
        for (int cc = 0; cc < DH; ++cc) s += q_lds[t * DH + cc] * bp[t * DH + cc];
        qbp[(size_t)n * HH + t] = s;
    }
}

// ---------------- Kernel B: scores_e = q . k^T per head (runs alone; kf L2-hot) ----------------
// grid = 512: b = h*64 + nt*8 + mt; 64x64 tile; writes esc[n][h][m]
__global__ __launch_bounds__(256) void escore_kernel(
    const float* __restrict__ qf, const float* __restrict__ kf, float* __restrict__ esc)
{
    const int b = blockIdx.x;
    const int h = b >> 6, nt = (b >> 3) & 7, mt = b & 7;
    const int n0 = nt * 64, m0 = mt * 64;
    const int t = threadIdx.x;

    __shared__ float q_t[64][33];
    __shared__ float k_t[64][33];

    #pragma unroll
    for (int it = 0; it < 2; ++it) {
        int idx = t + it * 256;
        int row = idx >> 3, c4 = (idx & 7) * 4;
        float4 qv = *reinterpret_cast<const float4*>(qf + (size_t)(n0 + row) * CC + h * DH + c4);
        float4 kv = *reinterpret_cast<const float4*>(kf + (size_t)(m0 + row) * CC + h * DH + c4);
        q_t[row][c4] = qv.x; q_t[row][c4+1] = qv.y; q_t[row][c4+2] = qv.z; q_t[row][c4+3] = qv.w;
        k_t[row][c4] = kv.x; k_t[row][c4+1] = kv.y; k_t[row][c4+2] = kv.z; k_t[row][c4+3] = kv.w;
    }
    __syncthreads();

    const int tx = t & 15, ty = t >> 4;
    float acc[4][4];
    #pragma unroll
    for (int i = 0; i < 4; ++i)
        #pragma unroll
        for (int jq = 0; jq < 4; ++jq) acc[i][jq] = 0.f;

    for (int cc = 0; cc < DH; ++cc) {
        float qa[4], kb[4];
        #pragma unroll
        for (int i = 0; i < 4; ++i) qa[i] = q_t[ty * 4 + i][cc];
        #pragma unroll
        for (int jq = 0; jq < 4; ++jq) kb[jq] = k_t[tx * 4 + jq][cc];
        #pragma unroll
        for (int i = 0; i < 4; ++i)
            #pragma unroll
            for (int jq = 0; jq < 4; ++jq) acc[i][jq] += qa[i] * kb[jq];
    }

    #pragma unroll
    for (int i = 0; i < 4; ++i) {
        float4 v = {acc[i][0], acc[i][1], acc[i][2], acc[i][3]};
        *reinterpret_cast<float4*>(
            esc + ((size_t)(n0 + ty * 4 + i) * HH + h) * NN + m0 + tx * 4) = v;
    }
}

// 16-lane tree reduce of 8 head-partials; lane c (0..15) ends with head
// h = (c&1)*4 + (c&2) + ((c>>2)&1) in u0 (valid for c<8; c>=8 duplicates).
__device__ __forceinline__ float reduce8(const float a[HH], int c) {
    const bool b1 = (c & 1), b2 = (c & 2), b4 = (c & 4);
    float t0 = b1 ? a[0] : a[4], t1 = b1 ? a[1] : a[5],
          t2 = b1 ? a[2] : a[6], t3 = b1 ? a[3] : a[7];
    float r0 = (b1 ? a[4] : a[0]) + __shfl_xor(t0, 1);
    float r1 = (b1 ? a[5] : a[1]) + __shfl_xor(t1, 1);
    float r2 = (b1 ? a[6] : a[2]) + __shfl_xor(t2, 1);
    float r3 = (b1 ? a[7] : a[3]) + __shfl_xor(t3, 1);
    t0 = b2 ? r0 : r2; t1 = b2 ? r1 : r3;
    float s0 = (b2 ? r2 : r0) + __shfl_xor(t0, 2);
    float s1 = (b2 ? r3 : r1) + __shfl_xor(t1, 2);
    t0 = b4 ? s0 : s1;
    float u0 = (b4 ? s1 : s0) + __shfl_xor(t0, 4);
    u0 += __shfl_xor(u0, 8);
    return u0;
}

// ---------------- Kernel C: scores_p = E . qw, full-row wave bursts ----------------
// grid = 4096: block b -> (n = b>>3, slab = b&7); block = 256 (4 waves).
// Wave v reads rows [slab*64 + v*16, +16); ONE instruction = ONE full 1KB row.
// PLAIN cached loads (no nontemporal): nt bypassed L2/L3 and pinned the
// stream at ~2.9 TB/s; round-1 (no nt) demonstrated 3.2-3.6 TB/s reads.
__global__ __launch_bounds__(256, 4) void estream_kernel(
    const float* __restrict__ E, const float* __restrict__ qw,
    float* __restrict__ scores)
{
    const int b = blockIdx.x;
    const int n = b >> 3, slab = b & 7;
    const int m0 = slab * 64;
    const int t = threadIdx.x;
    const int v = t >> 6, l = t & 63;
    const int c = l & 15;

    __shared__ float s_out[HH][68];       // 2.2 KB

    // qw fragments for this lane's column: 8 heads x float4 = 32 VGPRs (L2-hot)
    vf4 qwr[HH];
    #pragma unroll
    for (int h = 0; h < HH; ++h)
        qwr[h] = *reinterpret_cast<const vf4*>(qw + ((size_t)n * HH + h) * CC + l * 4);

    const float* Ebase = E + ((size_t)n * NN + m0 + v * 16) * CC;

    #pragma unroll
    for (int g = 0; g < 4; ++g) {
        // 4 rows in flight, each row one full-KB wave burst
        vf4 e4[4];
        #pragma unroll
        for (int it = 0; it < 4; ++it)
            e4[it] = *reinterpret_cast<const vf4*>(
                Ebase + (size_t)(g * 4 + it) * CC + l * 4);

        #pragma unroll
        for (int it = 0; it < 4; ++it) {
            float a[HH];
            #pragma unroll
            for (int h = 0; h < HH; ++h)
                a[h] = e4[it][0]*qwr[h][0] + e4[it][1]*qwr[h][1] +
                       e4[it][2]*qwr[h][2] + e4[it][3]*qwr[h][3];
            // reduce within 16-lane groups, then across the 4 groups
            float u0 = reduce8(a, c);
            u0 += __shfl_xor(u0, 16);
            u0 += __shfl_xor(u0, 32);
            if (l < 8) {
                int h = (c & 1) * 4 + (c & 2) + ((c >> 2) & 1);
                s_out[h][v * 16 + g * 4 + it] = u0;
            }
        }
    }
    __syncthreads();

    // coalesced flush: scores[n][h][m0+row]
    {
        int h0 = t >> 6, row = t & 63;
        scores[((size_t)n * HH + h0) * NN + m0 + row] = s_out[h0][row];
        int h1 = h0 + 4;
        scores[((size_t)n * HH + h1) * NN + m0 + row] = s_out[h1][row];
    }
}

// ---------------- Kernel D: softmax(esc + scores) + attn write + hidden ----------------
// grid = 512 (one n per block), block = 512; wave w handles head w
__global__ __launch_bounds__(512) void softmax_hidden_kernel(
    const float* __restrict__ esc, const float* __restrict__ scores,
    const float* __restrict__ qbp, const float* __restrict__ vf,
    float* __restrict__ attn_out, float* __restrict__ out_hidden)
{
    const int n = blockIdx.x;
    const int t = threadIdx.x;
    const int w = t >> 6, l = t & 63;

    __shared__ float s_lds[HH][NN + 4];   // 16.1 KB (probs)
    __shared__ float part_lds[HH][CC];    // 8 KB (hidden partials)

    {
        const int h = w;
        const float qb = qbp[(size_t)n * HH + h];
        const float scale = 0.17677669529663687f;  // 1/sqrt(32)
        const float* ep = esc    + ((size_t)n * HH + h) * NN;
        const float* sp = scores + ((size_t)n * HH + h) * NN;
        float vals[8];
        float mx = -1e30f;
        #pragma unroll
        for (int i = 0; i < 8; ++i) {
            vals[i] = (ep[l + i * 64] + sp[l + i * 64] + qb) * scale;
            mx = fmaxf(mx, vals[i]);
        }
        #pragma unroll
        for (int off = 32; off > 0; off >>= 1) mx = fmaxf(mx, __shfl_xor(mx, off));
        float sum = 0.f;
        #pragma unroll
        for (int i = 0; i < 8; ++i) { vals[i] = __expf(vals[i] - mx); sum += vals[i]; }
        #pragma unroll
        for (int off = 32; off > 0; off >>= 1) sum += __shfl_xor(sum, off);
        float inv = 1.0f / sum;
        #pragma unroll
        for (int i = 0; i < 8; ++i) {
            float p = vals[i] * inv;
            int m = l + i * 64;
            s_lds[h][m] = p;
            __builtin_nontemporal_store(p, attn_out + ((size_t)h * NN + n) * NN + m);
        }
    }
    __syncthreads();

    // hidden[n][j] = sum_m attn[h][m] * v[m][j], h = j>>5 (E done -> vf stays in L2)
    {
        const int quad = t & 63;           // output cols quad*4..quad*4+3
        const int slice = w;               // m slice of 64
        const int h = quad >> 3;
        float4 a4 = {0.f, 0.f, 0.f, 0.f};
        const float* vb = vf + quad * 4;
        for (int mm = 0; mm < 64; ++mm) {
            int m = slice * 64 + mm;
            float a = s_lds[h][m];
            float4 vv = *reinterpret_cast<const float4*>(vb + (size_t)m * CC);
            a4.x += a * vv.x; a4.y += a * vv.y; a4.z += a * vv.z; a4.w += a * vv.w;
        }
        *reinterpret_cast<float4*>(&part_lds[slice][quad * 4]) = a4;
    }
    __syncthreads();
    if (t < 256) {
        float s = 0.f;
        #pragma unroll
        for (int sl = 0; sl < 8; ++sl) s += part_lds[sl][t];
        out_hidden[(size_t)n * CC + t] = s;
    }
}

// ---------------- launch ----------------
extern "C" void kernel_launch(void* const* d_in, const int* in_sizes, int n_in,
                              void* d_out, int out_size, void* d_ws, size_t ws_size,
                              hipStream_t stream) {
    const float* xq = (const float*)d_in[0];
    const float* xk = (const float*)d_in[1];
    const float* xv = (const float*)d_in[2];
    const float* E  = (const float*)d_in[3];
    const float* Wq = (const float*)d_in[4];
    const float* bq = (const float*)d_in[5];
    const float* Wk = (const float*)d_in[6];
    const float* bk = (const float*)d_in[7];
    const float* Wv = (const float*)d_in[8];
    const float* bv = (const float*)d_in[9];
    const float* Wp = (const float*)d_in[10];
    const float* bp = (const float*)d_in[11];

    float* ws = (float*)d_ws;
    float* qf     = ws;                          // 512*256
    float* kf     = qf + NN * CC;                // 512*256
    float* vf     = kf + NN * CC;                // 512*256
    float* qw     = vf + NN * CC;                // 512*8*256
    float* qbp    = qw + (size_t)NN * HH * CC;   // 512*8
    float* esc    = qbp + NN * HH;               // 512*8*512 (q.k^T scores)
    float* scores = esc + (size_t)NN * HH * NN;  // 512*8*512 (E.qw scores)

    float* out_hidden = (float*)d_out;            // 512*256
    float* out_attn   = out_hidden + NN * CC;     // 8*512*512

    proj_kernel<<<NN, 256, 0, stream>>>(xq, xk, xv, Wq, bq, Wk, bk, Wv, bv, Wp, bp,
                                        qf, kf, vf, qw, qbp);
    escore_kernel<<<512, 256, 0, stream>>>(qf, kf, esc);
    estream_kernel<<<NN * 8, 256, 0, stream>>>(E, qw, scores);
    softmax_hidden_kernel<<<NN, 512, 0, stream>>>(esc, scores, qbp, vf,
                                                  out_attn, out_hidden);
}